// Round 1
// 414.110 us; speedup vs baseline: 1.0358x; 1.0358x over previous
//
#include <hip/hip_runtime.h>
#include <math.h>

// EntmaxBisect, d=4096, alpha=1.5, p=1/4095 (faithful to source).
//
// Collapse: every positive term u^p with p=1/4095 lies in [0.975, 1), so
// sum(Z) >= 1  <=>  at least 2 elements above t  <=>  second_max(Xs) > t.
// The 50-iteration bisection is therefore a pure scalar binary search toward
// second_max — no per-iteration reduction needed. Early-exit when
// fl(t_min+diff)==t_min is bit-equivalent to finishing all 50 iterations.
//
// This revision (memory-path polish, bit-identical arithmetic):
//  - nontemporal float4 loads/stores: both 256 MiB streams are touch-once,
//    nt skips cache allocation so the mixed read+write stream can approach
//    the pure-fill HBM rate (~6.3 TB/s).
//  - wave-ballot skip of pow: <=2 positive elements per row => 15/16 slots
//    per wave skip v_log/v_exp entirely; z cached between sum and epilogue
//    so pow is computed once. Adding +0.0f to a non-negative accumulator and
//    0.0f*rsum are bit-identical to the previous branch forms (absmax 0.0).

static constexpr int D = 4096;
static constexpr int NT = 256;
static constexpr float P = (float)(1.0 / 4095.0);   // matches f32(1.0/(d-1))

typedef float vf4 __attribute__((ext_vector_type(4)));

__device__ __forceinline__ float pow_p(float u) {
#if __has_builtin(__builtin_amdgcn_exp2f) && __has_builtin(__builtin_amdgcn_logf)
    return __builtin_amdgcn_exp2f(P * __builtin_amdgcn_logf(u));
#else
    return exp2f(P * log2f(u));
#endif
}

__device__ __forceinline__ float wave_sum(float v) {
#pragma unroll
    for (int k = 32; k >= 1; k >>= 1) v += __shfl_xor(v, k, 64);
    return v;
}

__device__ __forceinline__ void top2_merge(float& hi, float& lo, float ohi, float olo) {
    float nhi = fmaxf(hi, ohi);
    float nlo = fmaxf(fminf(hi, ohi), fmaxf(lo, olo));
    hi = nhi; lo = nlo;
}

__global__ void __launch_bounds__(NT) entmax_bisect_kernel(
        const float* __restrict__ X, float* __restrict__ out) {
    __shared__ float s_hi[4], s_lo[4], s_sum[4];

    const int tid  = threadIdx.x;
    const int lane = tid & 63;
    const int wid  = tid >> 6;
    const size_t rowbase = (size_t)blockIdx.x * D;
    const vf4* Xv = (const vf4*)(X + rowbase);
    vf4*       Ov = (vf4*)(out + rowbase);

    // ---- load row (nontemporal), scale by (alpha-1)=0.5 (exact) ----
    vf4 xs[4];
#pragma unroll
    for (int c = 0; c < 4; ++c) {
        vf4 v = __builtin_nontemporal_load(Xv + c * NT + tid);
        xs[c] = 0.5f * v;
    }

    // ---- per-thread top-2 ----
    float hi = -3.4e38f, lo = -3.4e38f;
#pragma unroll
    for (int c = 0; c < 4; ++c) {
#pragma unroll
        for (int j = 0; j < 4; ++j) {
            float v = xs[c][j];
            if (v > hi) { lo = hi; hi = v; }
            else        { lo = fmaxf(lo, v); }
        }
    }
    // ---- wave top-2 (butterfly pair-merge) ----
#pragma unroll
    for (int k = 32; k >= 1; k >>= 1) {
        float ohi = __shfl_xor(hi, k, 64);
        float olo = __shfl_xor(lo, k, 64);
        top2_merge(hi, lo, ohi, olo);
    }
    if (lane == 0) { s_hi[wid] = hi; s_lo[wid] = lo; }
    __syncthreads();
    // ---- block top-2 (uniform on all threads) ----
    float m = s_hi[0], s2 = s_lo[0];
#pragma unroll
    for (int w = 1; w < 4; ++w) top2_merge(m, s2, s_hi[w], s_lo[w]);

    // ---- scalar bisection, redundantly on every thread (wave-uniform) ----
    float t_min = m - 1.0f;
    float diff  = (m - 0.015625f) - t_min;   // t_max - t_min, f32 as in ref
    float t     = t_min;
#pragma unroll 1
    for (int it = 0; it < 50; ++it) {
        diff *= 0.5f;                  // exact
        t = t_min + diff;
        if (t == t_min) break;         // all remaining iterations are no-ops
        if (t < s2) t_min = t;         // == (sum(Z(t)) - 1 >= 0), see header
    }

    // ---- Z at the last probed t; pow only when some lane in the wave has
    //      a positive u (<=2 per row => 15/16 slots skip v_log/v_exp) ----
    float local = 0.0f;
    vf4 z[4];
#pragma unroll
    for (int c = 0; c < 4; ++c) {
#pragma unroll
        for (int j = 0; j < 4; ++j) {
            float u  = xs[c][j] - t;
            float zz = 0.0f;
            if (__ballot(u > 0.0f) != 0ull) {   // wave-uniform skip
                if (u > 0.0f) zz = pow_p(u);
            }
            z[c][j] = zz;
            local  += zz;                        // +0.0f is bit-exact no-op
        }
    }
    local = wave_sum(local);
    if (lane == 0) s_sum[wid] = local;
    __syncthreads();
    const float rsum = 1.0f / (s_sum[0] + s_sum[1] + s_sum[2] + s_sum[3]);

    // ---- epilogue: cached z * rsum, nontemporal coalesced float4 stores ----
#pragma unroll
    for (int c = 0; c < 4; ++c) {
        vf4 o;
#pragma unroll
        for (int j = 0; j < 4; ++j) o[j] = z[c][j] * rsum;  // 0*rsum == 0.0f
        __builtin_nontemporal_store(o, Ov + c * NT + tid);
    }
}

extern "C" void kernel_launch(void* const* d_in, const int* in_sizes, int n_in,
                              void* d_out, int out_size, void* d_ws, size_t ws_size,
                              hipStream_t stream) {
    const float* X = (const float*)d_in[0];
    float* O = (float*)d_out;
    const int nrows = in_sizes[0] / D;
    hipLaunchKernelGGL(entmax_bisect_kernel, dim3(nrows), dim3(NT), 0, stream, X, O);
}